// Round 9
// baseline (253.983 us; speedup 1.0000x reference)
//
#include <hip/hip_runtime.h>
#include <hip/hip_bf16.h>
#include <hip/hip_fp8.h>

#define D_IN 128
#define D_H  256
#define NBLK 128            // edge-chunk blocks for hist/place (must match!)
#define BSH  7              // 128 nodes per bucket
#define BNODES 128
#define MAXCH 6400          // max edges per chunk block (E=800000/128=6250)

typedef __attribute__((ext_vector_type(8))) short short8;   // 8 bf16 (4 VGPRs)
typedef __attribute__((ext_vector_type(4))) float floatx4;  // MFMA C/D frag
typedef __attribute__((ext_vector_type(4))) unsigned short ushortx4; // native vec (nontemporal-ok)

__device__ __forceinline__ unsigned short f2bf(float f) {
    __hip_bfloat16 h = __float2bfloat16(f);
    return *reinterpret_cast<unsigned short*>(&h);
}
__device__ __forceinline__ unsigned char f2fp8(float f) {
    __hip_fp8_e4m3 t(f);
    return (unsigned char)t.__x;
}

// exclusive scan of vals[0..NB) in place (NB<=512, 256 threads), part[256] scratch
__device__ __forceinline__ void excl_scan512(int* vals, int NB, int* part) {
    const int t = threadIdx.x;
    const int i0 = t * 2, i1 = t * 2 + 1;
    int v0 = (i0 < NB) ? vals[i0] : 0;
    int v1 = (i1 < NB) ? vals[i1] : 0;
    part[t] = v0 + v1;
    __syncthreads();
    for (int off = 1; off < 256; off <<= 1) {
        int u = (t >= off) ? part[t - off] : 0;
        __syncthreads();
        part[t] += u;
        __syncthreads();
    }
    const int pre = (t == 0) ? 0 : part[t - 1];
    if (i0 < NB) vals[i0] = pre;
    if (i1 < NB) vals[i1] = pre + v0;
    __syncthreads();
}

// ---- P1: LDS bucket histogram (blocks < NBLK, blocked chunks) + casts -----
__global__ void p1_hist_conv_k(const int* __restrict__ dst, int* __restrict__ cnt2d,
                               int E, int NB,
                               const float* __restrict__ x,
                               unsigned char* __restrict__ xb8, int nx4,
                               const float* __restrict__ w1l, unsigned short* __restrict__ w1lb,
                               const float* __restrict__ w1r, unsigned short* __restrict__ w1rb, int nw14,
                               const float* __restrict__ w2l, unsigned short* __restrict__ w2lb,
                               const float* __restrict__ w2r, unsigned short* __restrict__ w2rb, int nw24) {
    if (blockIdx.x < NBLK) {
        __shared__ int h[512];                  // NB <= 512
        for (int i = threadIdx.x; i < NB; i += 256) h[i] = 0;
        __syncthreads();
        const int CH = (E + NBLK - 1) / NBLK;
        const int e0 = blockIdx.x * CH;
        const int e1 = min(e0 + CH, E);
        for (int e = e0 + threadIdx.x; e < e1; e += 256)
            atomicAdd(&h[dst[e] >> BSH], 1);    // LDS atomic (fast)
        __syncthreads();
        for (int i = threadIdx.x; i < NB; i += 256)
            cnt2d[blockIdx.x * NB + i] = h[i];
        return;
    }
    int i = (blockIdx.x - NBLK) * 256 + threadIdx.x;
    if (i < nx4) {
        float4 v = ((const float4*)x)[i];
        uchar4 c;
        c.x = f2fp8(v.x); c.y = f2fp8(v.y); c.z = f2fp8(v.z); c.w = f2fp8(v.w);
        ((uchar4*)xb8)[i] = c;
        return;
    }
    i -= nx4;
    const float* s; unsigned short* d; int k;
    if (i < nw14) { s = w1l; d = w1lb; k = i; }
    else {
        i -= nw14;
        if (i < nw14) { s = w1r; d = w1rb; k = i; }
        else {
            i -= nw14;
            if (i < nw24) { s = w2l; d = w2lb; k = i; }
            else {
                i -= nw24;
                if (i >= nw24) return;
                s = w2r; d = w2rb; k = i;
            }
        }
    }
    float4 v = ((const float4*)s)[k];
    ushort4 u;
    u.x = f2bf(v.x); u.y = f2bf(v.y); u.z = f2bf(v.z); u.w = f2bf(v.w);
    ((ushort4*)d)[k] = u;
}

// ---- S1: per-bucket scan over the NBLK block counts -----------------------
__global__ __launch_bounds__(NBLK) void bucket_scan_k(const int* __restrict__ cnt2d,
                                                      int* __restrict__ off2d,
                                                      int* __restrict__ tot, int NB) {
    const int B = blockIdx.x, t = threadIdx.x;
    __shared__ int sc[NBLK];
    __shared__ int orig[NBLK];
    int v = cnt2d[t * NB + B];
    orig[t] = v; sc[t] = v;
    __syncthreads();
    for (int off = 1; off < NBLK; off <<= 1) {
        int u = (t >= off) ? sc[t - off] : 0;
        __syncthreads();
        sc[t] += u;
        __syncthreads();
    }
    off2d[t * NB + B] = sc[t] - orig[t];
    if (t == NBLK - 1) tot[B] = sc[t];
}

// ---- P2: two-level multi-split; local counts come from cnt2d (no re-hist) -
// pack = dst<<16 | src (both < 65536).
__global__ __launch_bounds__(256) void place_k(const int* __restrict__ src,
                                               const int* __restrict__ dst,
                                               const int* __restrict__ cnt2d,
                                               const int* __restrict__ off2d,
                                               const int* __restrict__ tot,
                                               unsigned int* __restrict__ staging,
                                               int E, int NB) {
    __shared__ unsigned int lstage[MAXCH];
    __shared__ int lstart[512], lcur[512], runstart[512];
    __shared__ int part[256];
    const int b = blockIdx.x, tid = threadIdx.x;
    const int CH = (E + NBLK - 1) / NBLK;
    const int e0 = b * CH;
    const int e1 = min(e0 + CH, E);
    const int n = e1 - e0;

    for (int i = tid; i < NB; i += 256) {
        lstart[i] = cnt2d[b * NB + i];          // local counts, precomputed in p1
        runstart[i] = tot[i];
    }
    __syncthreads();
    excl_scan512(lstart, NB, part);             // lstart = local excl prefix
    excl_scan512(runstart, NB, part);           // runstart = global bucket base
    for (int i = tid; i < NB; i += 256) {
        runstart[i] += off2d[b * NB + i];       // + this block's offset in bucket
        lcur[i] = lstart[i];
    }
    __syncthreads();
    for (int e = e0 + tid; e < e1; e += 256) {
        const int d = dst[e];
        const int pos = atomicAdd(&lcur[d >> BSH], 1);
        lstage[pos] = ((unsigned int)d << 16) | (unsigned int)src[e];
    }
    __syncthreads();
    for (int i = tid; i < n; i += 256) {
        const unsigned int u = lstage[i];
        const int bkt = (int)(u >> (16 + BSH));
        staging[runstart[bkt] + (i - lstart[bkt])] = u;
    }
}

// ---- P3: per-bucket counting sort -> rp + col -----------------------------
__global__ __launch_bounds__(256) void bucket_sort_k(const unsigned int* __restrict__ staging,
                                                     const int* __restrict__ tot,
                                                     int* __restrict__ rp, int* __restrict__ col,
                                                     int M, int NB) {
    const int B = blockIdx.x, tid = threadIdx.x;
    __shared__ int red[256];
    __shared__ int h[BNODES], sc[BNODES], cur[BNODES];
    __shared__ int s0s, s1s;
    int acc = 0;
    for (int i = tid; i < B; i += 256) acc += tot[i];
    red[tid] = acc; __syncthreads();
    for (int off = 128; off > 0; off >>= 1) {
        if (tid < off) red[tid] += red[tid + off];
        __syncthreads();
    }
    if (tid == 0) { s0s = red[0]; s1s = red[0] + tot[B]; }
    if (tid < BNODES) h[tid] = 0;
    __syncthreads();
    const int s0 = s0s, s1 = s1s;
    for (int i = s0 + tid; i < s1; i += 256)
        atomicAdd(&h[(staging[i] >> 16) & (BNODES - 1)], 1);
    __syncthreads();
    if (tid < BNODES) sc[tid] = h[tid];
    __syncthreads();
    for (int off = 1; off < BNODES; off <<= 1) {
        int v = 0;
        if (tid < BNODES && tid >= off) v = sc[tid - off];
        __syncthreads();
        if (tid < BNODES) sc[tid] += v;
        __syncthreads();
    }
    if (tid < BNODES) {
        const int excl = sc[tid] - h[tid];
        const int node = B * BNODES + tid;
        if (node < M) rp[node] = s0 + excl;
        cur[tid] = s0 + excl;
    }
    if (B == NB - 1 && tid == 0) rp[M] = s1;    // == E
    __syncthreads();
    for (int i = s0 + tid; i < s1; i += 256) {
        const unsigned int u = staging[i];
        const int pos = atomicAdd(&cur[(u >> 16) & (BNODES - 1)], 1);
        col[pos] = (int)(u & 0xFFFFu);
    }
}

// ------------- agg layer 1: fp8 d=128, half-wave pair gather ---------------
template <int UNP>
__device__ __forceinline__ int agg1_stage(const unsigned char* __restrict__ X8,
                                          const int* __restrict__ col,
                                          int j, int e, int sel, int l32, float* acc) {
    for (; j + 2 * UNP <= e; j += 2 * UNP) {
        int c0[UNP], c1[UNP];
#pragma unroll
        for (int u = 0; u < UNP; ++u) {
            c0[u] = __builtin_nontemporal_load(col + j + 2 * u);
            c1[u] = __builtin_nontemporal_load(col + j + 2 * u + 1);
        }
        unsigned int vals[UNP];
#pragma unroll
        for (int u = 0; u < UNP; ++u) {
            const int cs = sel ? c1[u] : c0[u];
            vals[u] = *(const unsigned int*)(X8 + (size_t)cs * 128 + l32 * 4);
        }
#pragma unroll
        for (int u = 0; u < UNP; ++u) {
            __hip_fp8x4_e4m3 p;
            p.__x = vals[u];
            float4 f = (float4)p;
            acc[0] += f.x; acc[1] += f.y; acc[2] += f.z; acc[3] += f.w;
        }
    }
    return j;
}

__global__ __launch_bounds__(256) void aggregate1_k(
    const unsigned char* __restrict__ X8, const int* __restrict__ col,
    const int* __restrict__ rp, unsigned short* __restrict__ out, int Mnodes) {
    int node = __builtin_amdgcn_readfirstlane((blockIdx.x << 2) + (threadIdx.x >> 6));
    if (node >= Mnodes) return;
    const int lane = threadIdx.x & 63;
    const int sel = lane >> 5;
    const int l32 = lane & 31;
    const int s = rp[node], e = rp[node + 1];
    float acc[4] = {0.f, 0.f, 0.f, 0.f};

    int j = s;
    j = agg1_stage<4>(X8, col, j, e, sel, l32, acc);
    j = agg1_stage<2>(X8, col, j, e, sel, l32, acc);
    j = agg1_stage<1>(X8, col, j, e, sel, l32, acc);
    if (j < e) {
        const int c0 = col[j];
        if (sel == 0) {
            unsigned int v = *(const unsigned int*)(X8 + (size_t)c0 * 128 + l32 * 4);
            __hip_fp8x4_e4m3 p;
            p.__x = v;
            float4 f = (float4)p;
            acc[0] += f.x; acc[1] += f.y; acc[2] += f.z; acc[3] += f.w;
        }
    }
#pragma unroll
    for (int k = 0; k < 4; ++k) acc[k] += __shfl_xor(acc[k], 32, 64);
    const float inv = 1.f / fmaxf((float)(e - s), 1.f);
    if (sel == 0) {
        ushortx4 o;
        o.x = f2bf(acc[0] * inv); o.y = f2bf(acc[1] * inv);
        o.z = f2bf(acc[2] * inv); o.w = f2bf(acc[3] * inv);
        __builtin_nontemporal_store(o, (ushortx4*)(out + (size_t)node * 128 + l32 * 4));
    }
}

// ------------- agg layer 2: fp8 d=256, full-wave ---------------------------
template <int UN>
__device__ __forceinline__ int agg_stage_fp8(const unsigned char* __restrict__ X8,
                                             const int* __restrict__ col,
                                             int j, int e, int lane, float* acc) {
    for (; j + UN <= e; j += UN) {
        int cs[UN];
#pragma unroll
        for (int u = 0; u < UN; ++u) cs[u] = __builtin_nontemporal_load(col + j + u);
        unsigned int vals[UN];
#pragma unroll
        for (int u = 0; u < UN; ++u)
            vals[u] = *(const unsigned int*)(X8 + (size_t)cs[u] * 256 + lane * 4);
#pragma unroll
        for (int u = 0; u < UN; ++u) {
            __hip_fp8x4_e4m3 p;
            p.__x = vals[u];
            float4 f = (float4)p;
            acc[0] += f.x; acc[1] += f.y; acc[2] += f.z; acc[3] += f.w;
        }
    }
    return j;
}

__global__ __launch_bounds__(256) void aggregate2_k(
    const unsigned char* __restrict__ X8, const int* __restrict__ col,
    const int* __restrict__ rp, unsigned short* __restrict__ out, int Mnodes) {
    int node = __builtin_amdgcn_readfirstlane((blockIdx.x << 2) + (threadIdx.x >> 6));
    if (node >= Mnodes) return;
    const int lane = threadIdx.x & 63;
    const int s = rp[node], e = rp[node + 1];
    float acc[4] = {0.f, 0.f, 0.f, 0.f};

    int j = s;
    j = agg_stage_fp8<8>(X8, col, j, e, lane, acc);
    j = agg_stage_fp8<4>(X8, col, j, e, lane, acc);
    j = agg_stage_fp8<2>(X8, col, j, e, lane, acc);
    j = agg_stage_fp8<1>(X8, col, j, e, lane, acc);

    const float inv = 1.f / fmaxf((float)(e - s), 1.f);
    ushortx4 o;
    o.x = f2bf(acc[0] * inv); o.y = f2bf(acc[1] * inv);
    o.z = f2bf(acc[2] * inv); o.w = f2bf(acc[3] * inv);
    __builtin_nontemporal_store(o, (ushortx4*)(out + (size_t)node * 256 + lane * 4));
}

// ---------------- dual-input bf16 MFMA GEMM, 64x256 tile, 782 blocks -------
// Depth-2 software pipeline with parity-static register buffers (X even
// chunks, Y odd): next+1 chunk's global loads are issued AFTER the second
// barrier, so each barrier's implicit vmcnt(0) drain waits on loads issued
// one full compute phase earlier (was: freshly issued -> full latency
// exposed every chunk). No register rotation copies (a copy would force an
// early vmcnt wait). Epilogue: LDS-staged coalesced stores (R8 win).
template <int K, bool HEAD, bool A2F32>
__global__ __launch_bounds__(256, 4) void gemm_mfma_k(
    const unsigned short* __restrict__ A1, const unsigned short* __restrict__ W1,
    const unsigned short* __restrict__ A2, const float* __restrict__ A2f,
    const unsigned short* __restrict__ W2,
    const float* __restrict__ bias, unsigned short* __restrict__ Hout,
    unsigned char* __restrict__ Hout8,
    const float* __restrict__ hw, const float* __restrict__ hb,
    float* __restrict__ out, int M) {
    __shared__ __align__(16) unsigned short sAll[64 * 256];   // 32 KB
    unsigned short* sA = sAll;                 // 64*40 = 2560 ushorts
    unsigned short* sB = sAll + 2560;          // 256*40 = 10240 ushorts
    __shared__ float head_acc[64];

    constexpr int NCK = K / 32;
    constexpr int NC = 2 * NCK;                // always even

    const int tid = threadIdx.x;
    const int wave = tid >> 6;
    const int lane = tid & 63;
    const int c = lane & 15;
    const int q = lane >> 4;
    const int m0 = blockIdx.x * 64;

    if (HEAD && tid < 64) head_acc[tid] = 0.f;

    floatx4 acc[4][4];
#pragma unroll
    for (int mi = 0; mi < 4; ++mi)
#pragma unroll
        for (int ni = 0; ni < 4; ++ni) acc[mi][ni] = (floatx4){0.f, 0.f, 0.f, 0.f};

    const int arow = tid >> 2;              // 64 rows, 4 segs x 8 elems
    const int aseg = (tid & 3) * 8;
    const int brow = tid >> 2;
    const int bseg = (tid & 3) * 8;
    int gr = m0 + arow;
    if (gr >= M) gr = M - 1;

    auto loadChunk = [&](int t, short8& a0, short8* b) {
        const unsigned short* Wp = (t >= NCK) ? W2 : W1;
        const int k0 = (t & (NCK - 1)) * 32;
        if (A2F32 && t >= NCK) {
            const float* p = A2f + (size_t)gr * K + k0 + aseg;
            float4 u0 = *(const float4*)(p);
            float4 u1 = *(const float4*)(p + 4);
            a0 = (short8){(short)f2bf(u0.x), (short)f2bf(u0.y), (short)f2bf(u0.z), (short)f2bf(u0.w),
                          (short)f2bf(u1.x), (short)f2bf(u1.y), (short)f2bf(u1.z), (short)f2bf(u1.w)};
        } else {
            const unsigned short* Ap = (t >= NCK) ? A2 : A1;
            a0 = *(const short8*)(Ap + (size_t)gr * K + k0 + aseg);
        }
#pragma unroll
        for (int i = 0; i < 4; ++i)
            b[i] = *(const short8*)(Wp + (size_t)(brow + i * 64) * K + k0 + bseg);
    };

    auto stage = [&](short8& a0, short8* b) {
        *(short8*)&sA[arow * 40 + aseg] = a0;
#pragma unroll
        for (int i = 0; i < 4; ++i)
            *(short8*)&sB[(brow + i * 64) * 40 + bseg] = b[i];
    };

    auto computePhase = [&]() {
        short8 af[4], bf[4];
#pragma unroll
        for (int mi = 0; mi < 4; ++mi)
            af[mi] = *(const short8*)&sA[(mi * 16 + c) * 40 + q * 8];
#pragma unroll
        for (int ni = 0; ni < 4; ++ni)
            bf[ni] = *(const short8*)&sB[(wave * 64 + ni * 16 + c) * 40 + q * 8];
#pragma unroll
        for (int mi = 0; mi < 4; ++mi)
#pragma unroll
            for (int ni = 0; ni < 4; ++ni)
                acc[mi][ni] = __builtin_amdgcn_mfma_f32_16x16x32_bf16(
                    af[mi], bf[ni], acc[mi][ni], 0, 0, 0);
    };

    short8 xa, xb_[4], ya, yb_[4];
    loadChunk(0, xa, xb_);
    loadChunk(1, ya, yb_);

#pragma unroll 1
    for (int t = 0; t < NC; t += 2) {
        // even chunk t (buffer X)
        __syncthreads();
        stage(xa, xb_);
        __syncthreads();
        if (t + 2 < NC) loadChunk(t + 2, xa, xb_);   // in flight across next phase
        computePhase();
        // odd chunk t+1 (buffer Y)
        __syncthreads();
        stage(ya, yb_);
        __syncthreads();
        if (t + 3 < NC) loadChunk(t + 3, ya, yb_);
        computePhase();
    }

    if (!HEAD) {
        // ---- pass 1: bf16 tile -> LDS -> coalesced 16B stores -------------
        __syncthreads();                        // sA/sB reads done everywhere
#pragma unroll
        for (int mi = 0; mi < 4; ++mi)
#pragma unroll
            for (int ni = 0; ni < 4; ++ni) {
                const int n = wave * 64 + ni * 16 + c;
                const float bv = bias[n];
#pragma unroll
                for (int reg = 0; reg < 4; ++reg) {
                    const int m = mi * 16 + q * 4 + reg;
                    sAll[m * 256 + n] = f2bf(fmaxf(acc[mi][ni][reg] + bv, 0.f));
                }
            }
        __syncthreads();
#pragma unroll
        for (int it = 0; it < 8; ++it) {
            const int eo = it * 2048 + tid * 8;     // element offset in tile
            const int m = m0 + (eo >> 8);
            if (m < M) {
                short8 vv = *(const short8*)&sAll[eo];
                __builtin_nontemporal_store(vv, (short8*)(Hout + (size_t)m * 256 + (eo & 255)));
            }
        }
        // ---- pass 2: fp8 tile -> LDS -> coalesced 16B stores --------------
        __syncthreads();
        unsigned char* s8 = (unsigned char*)sAll;   // 64*256 bytes = 16 KB
#pragma unroll
        for (int mi = 0; mi < 4; ++mi)
#pragma unroll
            for (int ni = 0; ni < 4; ++ni) {
                const int n = wave * 64 + ni * 16 + c;
                const float bv = bias[n];
#pragma unroll
                for (int reg = 0; reg < 4; ++reg) {
                    const int m = mi * 16 + q * 4 + reg;
                    s8[m * 256 + n] = f2fp8(fmaxf(acc[mi][ni][reg] + bv, 0.f));
                }
            }
        __syncthreads();
#pragma unroll
        for (int it = 0; it < 4; ++it) {
            const int bo = it * 4096 + tid * 16;    // byte offset in tile
            const int m = m0 + (bo >> 8);
            if (m < M) {
                uint4 vv = *(const uint4*)&s8[bo];
                *(uint4*)(Hout8 + (size_t)m * 256 + (bo & 255)) = vv;  // temporal: agg2 gathers
            }
        }
    } else {
#pragma unroll
        for (int mi = 0; mi < 4; ++mi) {
            float p[4] = {0.f, 0.f, 0.f, 0.f};
#pragma unroll
            for (int ni = 0; ni < 4; ++ni) {
                const int n = wave * 64 + ni * 16 + c;
                const float bv = bias[n];
                const float hv = hw[n];
#pragma unroll
                for (int reg = 0; reg < 4; ++reg)
                    p[reg] += fmaxf(acc[mi][ni][reg] + bv, 0.f) * hv;
            }
#pragma unroll
            for (int reg = 0; reg < 4; ++reg) {
                float v = p[reg];
                v += __shfl_xor(v, 1, 64);
                v += __shfl_xor(v, 2, 64);
                v += __shfl_xor(v, 4, 64);
                v += __shfl_xor(v, 8, 64);
                if (c == 0) atomicAdd(&head_acc[mi * 16 + q * 4 + reg], v);
            }
        }
        __syncthreads();
        if (tid < 64) {
            const int m = m0 + tid;
            if (m < M) out[m] = head_acc[tid] + hb[0];
        }
    }
}

// ---------------- launch ----------------
extern "C" void kernel_launch(void* const* d_in, const int* in_sizes, int n_in,
                              void* d_out, int out_size, void* d_ws, size_t ws_size,
                              hipStream_t stream) {
    const float* x    = (const float*)d_in[0];
    const int*   ei   = (const int*)d_in[1];
    const float* W1l  = (const float*)d_in[2];
    const float* b1   = (const float*)d_in[3];
    const float* W1r  = (const float*)d_in[4];
    const float* W2l  = (const float*)d_in[5];
    const float* b2   = (const float*)d_in[6];
    const float* W2r  = (const float*)d_in[7];
    const float* hw   = (const float*)d_in[8];
    const float* hb   = (const float*)d_in[9];
    float* out = (float*)d_out;

    const int M = in_sizes[0] / D_IN;       // 50000 (< 65536: packs in 16b)
    const int E = in_sizes[1] / 2;          // 800000 (chunk 6250 <= MAXCH)
    const int* src = ei;
    const int* dst = ei + E;
    const int NB = (M + BNODES - 1) / BNODES;   // 391 buckets

    size_t off = 0;
    auto alloc = [&](size_t bytes) -> void* {
        void* p = (char*)d_ws + off;
        off += (bytes + 255) & ~(size_t)255;
        return p;
    };
    int* cnt2d = (int*)alloc((size_t)NBLK * NB * 4);
    int* off2d = (int*)alloc((size_t)NBLK * NB * 4);
    int* tot   = (int*)alloc((size_t)NB * 4);
    unsigned int* staging = (unsigned int*)alloc((size_t)E * 4);
    int* rp    = (int*)alloc((size_t)(M + 1) * 4);
    int* col   = (int*)alloc((size_t)E * 4);
    unsigned char*  xb8   = (unsigned char*)alloc((size_t)M * D_IN);
    unsigned short* w1lb  = (unsigned short*)alloc((size_t)D_H * D_IN * 2);
    unsigned short* w1rb  = (unsigned short*)alloc((size_t)D_H * D_IN * 2);
    unsigned short* w2lb  = (unsigned short*)alloc((size_t)D_H * D_H * 2);
    unsigned short* w2rb  = (unsigned short*)alloc((size_t)D_H * D_H * 2);
    unsigned short* mean1 = (unsigned short*)alloc((size_t)M * D_IN * 2);
    unsigned short* h1    = (unsigned short*)alloc((size_t)M * D_H * 2);
    unsigned char*  h8    = (unsigned char*)alloc((size_t)M * D_H);
    unsigned short* mean2 = (unsigned short*)alloc((size_t)M * D_H * 2);

    // CSR build (no device-scope atomics) + conversions
    const int nx4 = (M * D_IN) / 4;
    const int nw14 = (D_H * D_IN) / 4;
    const int nw24 = (D_H * D_H) / 4;
    const int tot4 = nx4 + 2 * nw14 + 2 * nw24;
    const int convblk = (tot4 + 255) / 256;
    p1_hist_conv_k<<<NBLK + convblk, 256, 0, stream>>>(
        dst, cnt2d, E, NB,
        x, xb8, nx4, W1l, w1lb, W1r, w1rb, nw14, W2l, w2lb, W2r, w2rb, nw24);
    bucket_scan_k<<<NB, NBLK, 0, stream>>>(cnt2d, off2d, tot, NB);
    place_k<<<NBLK, 256, 0, stream>>>(src, dst, cnt2d, off2d, tot, staging, E, NB);
    bucket_sort_k<<<NB, 256, 0, stream>>>(staging, tot, rp, col, M, NB);

    const int nblk = (M + 63) / 64;         // 782 blocks: ~3 blocks/CU
    const int ablk = (M + 3) / 4;

    // layer 1 (gather from fp8 xb8; self path f32 x converted in staging)
    aggregate1_k<<<ablk, 256, 0, stream>>>(xb8, col, rp, mean1, M);
    gemm_mfma_k<D_IN, false, true><<<nblk, 256, 0, stream>>>(
        mean1, w1lb, nullptr, x, w1rb, b1, h1, h8, nullptr, nullptr, nullptr, M);

    // layer 2 + fused head (gather from fp8 h8; self path bf16 h1)
    aggregate2_k<<<ablk, 256, 0, stream>>>(h8, col, rp, mean2, M);
    gemm_mfma_k<D_H, true, false><<<nblk, 256, 0, stream>>>(
        mean2, w2lb, h1, nullptr, w2rb, b2, nullptr, nullptr, hw, hb, out, M);
}

// Round 10
// 220.600 us; speedup vs baseline: 1.1513x; 1.1513x over previous
//
#include <hip/hip_runtime.h>
#include <hip/hip_bf16.h>
#include <hip/hip_fp8.h>

#define D_IN 128
#define D_H  256
#define NBLK 256            // edge-chunk blocks for hist/place (must match!)
#define BSH  7              // 128 nodes per bucket
#define BNODES 128
#define MAXCH 3200          // max edges per chunk block (E=800000/256=3125)

typedef __attribute__((ext_vector_type(8))) short short8;   // 8 bf16 (4 VGPRs)
typedef __attribute__((ext_vector_type(4))) float floatx4;  // MFMA C/D frag
typedef __attribute__((ext_vector_type(4))) unsigned short ushortx4; // native vec (nontemporal-ok)

__device__ __forceinline__ unsigned short f2bf(float f) {
    __hip_bfloat16 h = __float2bfloat16(f);
    return *reinterpret_cast<unsigned short*>(&h);
}
__device__ __forceinline__ unsigned char f2fp8(float f) {
    __hip_fp8_e4m3 t(f);
    return (unsigned char)t.__x;
}

// exclusive scan of vals[0..NB) in place (NB<=512, 256 threads), part[256] scratch
__device__ __forceinline__ void excl_scan512(int* vals, int NB, int* part) {
    const int t = threadIdx.x;
    const int i0 = t * 2, i1 = t * 2 + 1;
    int v0 = (i0 < NB) ? vals[i0] : 0;
    int v1 = (i1 < NB) ? vals[i1] : 0;
    part[t] = v0 + v1;
    __syncthreads();
    for (int off = 1; off < 256; off <<= 1) {
        int u = (t >= off) ? part[t - off] : 0;
        __syncthreads();
        part[t] += u;
        __syncthreads();
    }
    const int pre = (t == 0) ? 0 : part[t - 1];
    if (i0 < NB) vals[i0] = pre;
    if (i1 < NB) vals[i1] = pre + v0;
    __syncthreads();
}

// ---- P1: LDS bucket histogram (blocks < NBLK, blocked chunks) + casts -----
__global__ void p1_hist_conv_k(const int* __restrict__ dst, int* __restrict__ cnt2d,
                               int E, int NB,
                               const float* __restrict__ x,
                               unsigned char* __restrict__ xb8, int nx4,
                               const float* __restrict__ w1l, unsigned short* __restrict__ w1lb,
                               const float* __restrict__ w1r, unsigned short* __restrict__ w1rb, int nw14,
                               const float* __restrict__ w2l, unsigned short* __restrict__ w2lb,
                               const float* __restrict__ w2r, unsigned short* __restrict__ w2rb, int nw24) {
    if (blockIdx.x < NBLK) {
        __shared__ int h[512];                  // NB <= 512
        for (int i = threadIdx.x; i < NB; i += 256) h[i] = 0;
        __syncthreads();
        const int CH = (E + NBLK - 1) / NBLK;
        const int e0 = blockIdx.x * CH;
        const int e1 = min(e0 + CH, E);
        for (int e = e0 + threadIdx.x; e < e1; e += 256)
            atomicAdd(&h[dst[e] >> BSH], 1);    // LDS atomic (fast)
        __syncthreads();
        for (int i = threadIdx.x; i < NB; i += 256)
            cnt2d[blockIdx.x * NB + i] = h[i];
        return;
    }
    int i = (blockIdx.x - NBLK) * 256 + threadIdx.x;
    if (i < nx4) {
        float4 v = ((const float4*)x)[i];
        uchar4 c;
        c.x = f2fp8(v.x); c.y = f2fp8(v.y); c.z = f2fp8(v.z); c.w = f2fp8(v.w);
        ((uchar4*)xb8)[i] = c;
        return;
    }
    i -= nx4;
    const float* s; unsigned short* d; int k;
    if (i < nw14) { s = w1l; d = w1lb; k = i; }
    else {
        i -= nw14;
        if (i < nw14) { s = w1r; d = w1rb; k = i; }
        else {
            i -= nw14;
            if (i < nw24) { s = w2l; d = w2lb; k = i; }
            else {
                i -= nw24;
                if (i >= nw24) return;
                s = w2r; d = w2rb; k = i;
            }
        }
    }
    float4 v = ((const float4*)s)[k];
    ushort4 u;
    u.x = f2bf(v.x); u.y = f2bf(v.y); u.z = f2bf(v.z); u.w = f2bf(v.w);
    ((ushort4*)d)[k] = u;
}

// ---- S1: per-bucket scan over the NBLK block counts -----------------------
__global__ __launch_bounds__(NBLK) void bucket_scan_k(const int* __restrict__ cnt2d,
                                                      int* __restrict__ off2d,
                                                      int* __restrict__ tot, int NB) {
    const int B = blockIdx.x, t = threadIdx.x;
    __shared__ int sc[NBLK];
    __shared__ int orig[NBLK];
    int v = cnt2d[t * NB + B];
    orig[t] = v; sc[t] = v;
    __syncthreads();
    for (int off = 1; off < NBLK; off <<= 1) {
        int u = (t >= off) ? sc[t - off] : 0;
        __syncthreads();
        sc[t] += u;
        __syncthreads();
    }
    off2d[t * NB + B] = sc[t] - orig[t];
    if (t == NBLK - 1) tot[B] = sc[t];
}

// ---- P2: two-level multi-split; local counts come from cnt2d (no re-hist) -
// pack = dst<<16 | src (both < 65536).
__global__ __launch_bounds__(256) void place_k(const int* __restrict__ src,
                                               const int* __restrict__ dst,
                                               const int* __restrict__ cnt2d,
                                               const int* __restrict__ off2d,
                                               const int* __restrict__ tot,
                                               unsigned int* __restrict__ staging,
                                               int E, int NB) {
    __shared__ unsigned int lstage[MAXCH];
    __shared__ int lstart[512], lcur[512], runstart[512];
    __shared__ int part[256];
    const int b = blockIdx.x, tid = threadIdx.x;
    const int CH = (E + NBLK - 1) / NBLK;
    const int e0 = b * CH;
    const int e1 = min(e0 + CH, E);
    const int n = e1 - e0;

    for (int i = tid; i < NB; i += 256) {
        lstart[i] = cnt2d[b * NB + i];          // local counts, precomputed in p1
        runstart[i] = tot[i];
    }
    __syncthreads();
    excl_scan512(lstart, NB, part);             // lstart = local excl prefix
    excl_scan512(runstart, NB, part);           // runstart = global bucket base
    for (int i = tid; i < NB; i += 256) {
        runstart[i] += off2d[b * NB + i];       // + this block's offset in bucket
        lcur[i] = lstart[i];
    }
    __syncthreads();
    for (int e = e0 + tid; e < e1; e += 256) {
        const int d = dst[e];
        const int pos = atomicAdd(&lcur[d >> BSH], 1);
        lstage[pos] = ((unsigned int)d << 16) | (unsigned int)src[e];
    }
    __syncthreads();
    for (int i = tid; i < n; i += 256) {
        const unsigned int u = lstage[i];
        const int bkt = (int)(u >> (16 + BSH));
        staging[runstart[bkt] + (i - lstart[bkt])] = u;
    }
}

// ---- P3: per-bucket counting sort -> rp + col -----------------------------
__global__ __launch_bounds__(256) void bucket_sort_k(const unsigned int* __restrict__ staging,
                                                     const int* __restrict__ tot,
                                                     int* __restrict__ rp, int* __restrict__ col,
                                                     int M, int NB) {
    const int B = blockIdx.x, tid = threadIdx.x;
    __shared__ int red[256];
    __shared__ int h[BNODES], sc[BNODES], cur[BNODES];
    __shared__ int s0s, s1s;
    int acc = 0;
    for (int i = tid; i < B; i += 256) acc += tot[i];
    red[tid] = acc; __syncthreads();
    for (int off = 128; off > 0; off >>= 1) {
        if (tid < off) red[tid] += red[tid + off];
        __syncthreads();
    }
    if (tid == 0) { s0s = red[0]; s1s = red[0] + tot[B]; }
    if (tid < BNODES) h[tid] = 0;
    __syncthreads();
    const int s0 = s0s, s1 = s1s;
    for (int i = s0 + tid; i < s1; i += 256)
        atomicAdd(&h[(staging[i] >> 16) & (BNODES - 1)], 1);
    __syncthreads();
    if (tid < BNODES) sc[tid] = h[tid];
    __syncthreads();
    for (int off = 1; off < BNODES; off <<= 1) {
        int v = 0;
        if (tid < BNODES && tid >= off) v = sc[tid - off];
        __syncthreads();
        if (tid < BNODES) sc[tid] += v;
        __syncthreads();
    }
    if (tid < BNODES) {
        const int excl = sc[tid] - h[tid];
        const int node = B * BNODES + tid;
        if (node < M) rp[node] = s0 + excl;
        cur[tid] = s0 + excl;
    }
    if (B == NB - 1 && tid == 0) rp[M] = s1;    // == E
    __syncthreads();
    for (int i = s0 + tid; i < s1; i += 256) {
        const unsigned int u = staging[i];
        const int pos = atomicAdd(&cur[(u >> 16) & (BNODES - 1)], 1);
        col[pos] = (int)(u & 0xFFFFu);
    }
}

// ------------- agg layer 1: fp8 d=128, half-wave pair gather ---------------
template <int UNP>
__device__ __forceinline__ int agg1_stage(const unsigned char* __restrict__ X8,
                                          const int* __restrict__ col,
                                          int j, int e, int sel, int l32, float* acc) {
    for (; j + 2 * UNP <= e; j += 2 * UNP) {
        int c0[UNP], c1[UNP];
#pragma unroll
        for (int u = 0; u < UNP; ++u) {
            c0[u] = __builtin_nontemporal_load(col + j + 2 * u);
            c1[u] = __builtin_nontemporal_load(col + j + 2 * u + 1);
        }
        unsigned int vals[UNP];
#pragma unroll
        for (int u = 0; u < UNP; ++u) {
            const int cs = sel ? c1[u] : c0[u];
            vals[u] = *(const unsigned int*)(X8 + (size_t)cs * 128 + l32 * 4);
        }
#pragma unroll
        for (int u = 0; u < UNP; ++u) {
            __hip_fp8x4_e4m3 p;
            p.__x = vals[u];
            float4 f = (float4)p;
            acc[0] += f.x; acc[1] += f.y; acc[2] += f.z; acc[3] += f.w;
        }
    }
    return j;
}

__global__ __launch_bounds__(256) void aggregate1_k(
    const unsigned char* __restrict__ X8, const int* __restrict__ col,
    const int* __restrict__ rp, unsigned short* __restrict__ out, int Mnodes) {
    int node = __builtin_amdgcn_readfirstlane((blockIdx.x << 2) + (threadIdx.x >> 6));
    if (node >= Mnodes) return;
    const int lane = threadIdx.x & 63;
    const int sel = lane >> 5;
    const int l32 = lane & 31;
    const int s = rp[node], e = rp[node + 1];
    float acc[4] = {0.f, 0.f, 0.f, 0.f};

    int j = s;
    j = agg1_stage<4>(X8, col, j, e, sel, l32, acc);
    j = agg1_stage<2>(X8, col, j, e, sel, l32, acc);
    j = agg1_stage<1>(X8, col, j, e, sel, l32, acc);
    if (j < e) {
        const int c0 = col[j];
        if (sel == 0) {
            unsigned int v = *(const unsigned int*)(X8 + (size_t)c0 * 128 + l32 * 4);
            __hip_fp8x4_e4m3 p;
            p.__x = v;
            float4 f = (float4)p;
            acc[0] += f.x; acc[1] += f.y; acc[2] += f.z; acc[3] += f.w;
        }
    }
#pragma unroll
    for (int k = 0; k < 4; ++k) acc[k] += __shfl_xor(acc[k], 32, 64);
    const float inv = 1.f / fmaxf((float)(e - s), 1.f);
    if (sel == 0) {
        ushortx4 o;
        o.x = f2bf(acc[0] * inv); o.y = f2bf(acc[1] * inv);
        o.z = f2bf(acc[2] * inv); o.w = f2bf(acc[3] * inv);
        __builtin_nontemporal_store(o, (ushortx4*)(out + (size_t)node * 128 + l32 * 4));
    }
}

// ------------- agg layer 2: fp8 d=256, full-wave ---------------------------
template <int UN>
__device__ __forceinline__ int agg_stage_fp8(const unsigned char* __restrict__ X8,
                                             const int* __restrict__ col,
                                             int j, int e, int lane, float* acc) {
    for (; j + UN <= e; j += UN) {
        int cs[UN];
#pragma unroll
        for (int u = 0; u < UN; ++u) cs[u] = __builtin_nontemporal_load(col + j + u);
        unsigned int vals[UN];
#pragma unroll
        for (int u = 0; u < UN; ++u)
            vals[u] = *(const unsigned int*)(X8 + (size_t)cs[u] * 256 + lane * 4);
#pragma unroll
        for (int u = 0; u < UN; ++u) {
            __hip_fp8x4_e4m3 p;
            p.__x = vals[u];
            float4 f = (float4)p;
            acc[0] += f.x; acc[1] += f.y; acc[2] += f.z; acc[3] += f.w;
        }
    }
    return j;
}

__global__ __launch_bounds__(256) void aggregate2_k(
    const unsigned char* __restrict__ X8, const int* __restrict__ col,
    const int* __restrict__ rp, unsigned short* __restrict__ out, int Mnodes) {
    int node = __builtin_amdgcn_readfirstlane((blockIdx.x << 2) + (threadIdx.x >> 6));
    if (node >= Mnodes) return;
    const int lane = threadIdx.x & 63;
    const int s = rp[node], e = rp[node + 1];
    float acc[4] = {0.f, 0.f, 0.f, 0.f};

    int j = s;
    j = agg_stage_fp8<8>(X8, col, j, e, lane, acc);
    j = agg_stage_fp8<4>(X8, col, j, e, lane, acc);
    j = agg_stage_fp8<2>(X8, col, j, e, lane, acc);
    j = agg_stage_fp8<1>(X8, col, j, e, lane, acc);

    const float inv = 1.f / fmaxf((float)(e - s), 1.f);
    ushortx4 o;
    o.x = f2bf(acc[0] * inv); o.y = f2bf(acc[1] * inv);
    o.z = f2bf(acc[2] * inv); o.w = f2bf(acc[3] * inv);
    __builtin_nontemporal_store(o, (ushortx4*)(out + (size_t)node * 256 + lane * 4));
}

// ---------------- dual-input bf16 MFMA GEMM, 64x256 tile, 782 blocks -------
// R8-proven structure: single-prefetch K-loop + LDS-staged coalesced epilogue
// (fixes 29% WRITE_SIZE amplification). R9's depth-2 parity pipeline REVERTED:
// it raised FETCH 19->30MB and bank conflicts 1.8->3.6M, +10us/dispatch —
// every barrier drains vmcnt(0), so deeper SW pipelining can't hold loads
// across compute at HIP source level.
template <int K, bool HEAD, bool A2F32>
__global__ __launch_bounds__(256, 4) void gemm_mfma_k(
    const unsigned short* __restrict__ A1, const unsigned short* __restrict__ W1,
    const unsigned short* __restrict__ A2, const float* __restrict__ A2f,
    const unsigned short* __restrict__ W2,
    const float* __restrict__ bias, unsigned short* __restrict__ Hout,
    unsigned char* __restrict__ Hout8,
    const float* __restrict__ hw, const float* __restrict__ hb,
    float* __restrict__ out, int M) {
    __shared__ __align__(16) unsigned short sAll[64 * 256];   // 32 KB
    unsigned short* sA = sAll;                 // 64*40 = 2560 ushorts
    unsigned short* sB = sAll + 2560;          // 256*40 = 10240 ushorts
    __shared__ float head_acc[64];

    constexpr int NCK = K / 32;
    constexpr int NC = 2 * NCK;

    const int tid = threadIdx.x;
    const int wave = tid >> 6;
    const int lane = tid & 63;
    const int c = lane & 15;
    const int q = lane >> 4;
    const int m0 = blockIdx.x * 64;

    if (HEAD && tid < 64) head_acc[tid] = 0.f;

    floatx4 acc[4][4];
#pragma unroll
    for (int mi = 0; mi < 4; ++mi)
#pragma unroll
        for (int ni = 0; ni < 4; ++ni) acc[mi][ni] = (floatx4){0.f, 0.f, 0.f, 0.f};

    const int arow = tid >> 2;              // 64 rows, 4 segs x 8 elems
    const int aseg = (tid & 3) * 8;
    const int brow = tid >> 2;
    const int bseg = (tid & 3) * 8;
    int gr = m0 + arow;
    if (gr >= M) gr = M - 1;

    auto loadChunk = [&](int t, short8& a0, short8* b) {
        const unsigned short* Wp = (t >= NCK) ? W2 : W1;
        const int k0 = (t & (NCK - 1)) * 32;
        if (A2F32 && t >= NCK) {
            const float* p = A2f + (size_t)gr * K + k0 + aseg;
            float4 u0 = *(const float4*)(p);
            float4 u1 = *(const float4*)(p + 4);
            a0 = (short8){(short)f2bf(u0.x), (short)f2bf(u0.y), (short)f2bf(u0.z), (short)f2bf(u0.w),
                          (short)f2bf(u1.x), (short)f2bf(u1.y), (short)f2bf(u1.z), (short)f2bf(u1.w)};
        } else {
            const unsigned short* Ap = (t >= NCK) ? A2 : A1;
            a0 = *(const short8*)(Ap + (size_t)gr * K + k0 + aseg);
        }
#pragma unroll
        for (int i = 0; i < 4; ++i)
            b[i] = *(const short8*)(Wp + (size_t)(brow + i * 64) * K + k0 + bseg);
    };

    short8 ca0, cb[4], na0, nb[4];
    loadChunk(0, ca0, cb);

#pragma unroll 1
    for (int t = 0; t < NC; ++t) {
        __syncthreads();
        *(short8*)&sA[arow * 40 + aseg] = ca0;
#pragma unroll
        for (int i = 0; i < 4; ++i)
            *(short8*)&sB[(brow + i * 64) * 40 + bseg] = cb[i];
        if (t + 1 < NC)
            loadChunk(t + 1, na0, nb);
        __syncthreads();

        short8 af[4], bf[4];
#pragma unroll
        for (int mi = 0; mi < 4; ++mi)
            af[mi] = *(const short8*)&sA[(mi * 16 + c) * 40 + q * 8];
#pragma unroll
        for (int ni = 0; ni < 4; ++ni)
            bf[ni] = *(const short8*)&sB[(wave * 64 + ni * 16 + c) * 40 + q * 8];
#pragma unroll
        for (int mi = 0; mi < 4; ++mi)
#pragma unroll
            for (int ni = 0; ni < 4; ++ni)
                acc[mi][ni] = __builtin_amdgcn_mfma_f32_16x16x32_bf16(
                    af[mi], bf[ni], acc[mi][ni], 0, 0, 0);

        ca0 = na0;
#pragma unroll
        for (int i = 0; i < 4; ++i) cb[i] = nb[i];
    }

    if (!HEAD) {
        // ---- pass 1: bf16 tile -> LDS -> coalesced 16B stores -------------
        __syncthreads();                        // sA/sB reads done everywhere
#pragma unroll
        for (int mi = 0; mi < 4; ++mi)
#pragma unroll
            for (int ni = 0; ni < 4; ++ni) {
                const int n = wave * 64 + ni * 16 + c;
                const float bv = bias[n];
#pragma unroll
                for (int reg = 0; reg < 4; ++reg) {
                    const int m = mi * 16 + q * 4 + reg;
                    sAll[m * 256 + n] = f2bf(fmaxf(acc[mi][ni][reg] + bv, 0.f));
                }
            }
        __syncthreads();
#pragma unroll
        for (int it = 0; it < 8; ++it) {
            const int eo = it * 2048 + tid * 8;     // element offset in tile
            const int m = m0 + (eo >> 8);
            if (m < M) {
                short8 vv = *(const short8*)&sAll[eo];
                __builtin_nontemporal_store(vv, (short8*)(Hout + (size_t)m * 256 + (eo & 255)));
            }
        }
        // ---- pass 2: fp8 tile -> LDS -> coalesced 16B stores --------------
        __syncthreads();
        unsigned char* s8 = (unsigned char*)sAll;   // 64*256 bytes = 16 KB
#pragma unroll
        for (int mi = 0; mi < 4; ++mi)
#pragma unroll
            for (int ni = 0; ni < 4; ++ni) {
                const int n = wave * 64 + ni * 16 + c;
                const float bv = bias[n];
#pragma unroll
                for (int reg = 0; reg < 4; ++reg) {
                    const int m = mi * 16 + q * 4 + reg;
                    s8[m * 256 + n] = f2fp8(fmaxf(acc[mi][ni][reg] + bv, 0.f));
                }
            }
        __syncthreads();
#pragma unroll
        for (int it = 0; it < 4; ++it) {
            const int bo = it * 4096 + tid * 16;    // byte offset in tile
            const int m = m0 + (bo >> 8);
            if (m < M) {
                uint4 vv = *(const uint4*)&s8[bo];
                *(uint4*)(Hout8 + (size_t)m * 256 + (bo & 255)) = vv;  // temporal: agg2 gathers
            }
        }
    } else {
#pragma unroll
        for (int mi = 0; mi < 4; ++mi) {
            float p[4] = {0.f, 0.f, 0.f, 0.f};
#pragma unroll
            for (int ni = 0; ni < 4; ++ni) {
                const int n = wave * 64 + ni * 16 + c;
                const float bv = bias[n];
                const float hv = hw[n];
#pragma unroll
                for (int reg = 0; reg < 4; ++reg)
                    p[reg] += fmaxf(acc[mi][ni][reg] + bv, 0.f) * hv;
            }
#pragma unroll
            for (int reg = 0; reg < 4; ++reg) {
                float v = p[reg];
                v += __shfl_xor(v, 1, 64);
                v += __shfl_xor(v, 2, 64);
                v += __shfl_xor(v, 4, 64);
                v += __shfl_xor(v, 8, 64);
                if (c == 0) atomicAdd(&head_acc[mi * 16 + q * 4 + reg], v);
            }
        }
        __syncthreads();
        if (tid < 64) {
            const int m = m0 + tid;
            if (m < M) out[m] = head_acc[tid] + hb[0];
        }
    }
}

// ---------------- launch ----------------
extern "C" void kernel_launch(void* const* d_in, const int* in_sizes, int n_in,
                              void* d_out, int out_size, void* d_ws, size_t ws_size,
                              hipStream_t stream) {
    const float* x    = (const float*)d_in[0];
    const int*   ei   = (const int*)d_in[1];
    const float* W1l  = (const float*)d_in[2];
    const float* b1   = (const float*)d_in[3];
    const float* W1r  = (const float*)d_in[4];
    const float* W2l  = (const float*)d_in[5];
    const float* b2   = (const float*)d_in[6];
    const float* W2r  = (const float*)d_in[7];
    const float* hw   = (const float*)d_in[8];
    const float* hb   = (const float*)d_in[9];
    float* out = (float*)d_out;

    const int M = in_sizes[0] / D_IN;       // 50000 (< 65536: packs in 16b)
    const int E = in_sizes[1] / 2;          // 800000 (chunk 3125 <= MAXCH)
    const int* src = ei;
    const int* dst = ei + E;
    const int NB = (M + BNODES - 1) / BNODES;   // 391 buckets

    size_t off = 0;
    auto alloc = [&](size_t bytes) -> void* {
        void* p = (char*)d_ws + off;
        off += (bytes + 255) & ~(size_t)255;
        return p;
    };
    int* cnt2d = (int*)alloc((size_t)NBLK * NB * 4);
    int* off2d = (int*)alloc((size_t)NBLK * NB * 4);
    int* tot   = (int*)alloc((size_t)NB * 4);
    unsigned int* staging = (unsigned int*)alloc((size_t)E * 4);
    int* rp    = (int*)alloc((size_t)(M + 1) * 4);
    int* col   = (int*)alloc((size_t)E * 4);
    unsigned char*  xb8   = (unsigned char*)alloc((size_t)M * D_IN);
    unsigned short* w1lb  = (unsigned short*)alloc((size_t)D_H * D_IN * 2);
    unsigned short* w1rb  = (unsigned short*)alloc((size_t)D_H * D_IN * 2);
    unsigned short* w2lb  = (unsigned short*)alloc((size_t)D_H * D_H * 2);
    unsigned short* w2rb  = (unsigned short*)alloc((size_t)D_H * D_H * 2);
    unsigned short* mean1 = (unsigned short*)alloc((size_t)M * D_IN * 2);
    unsigned short* h1    = (unsigned short*)alloc((size_t)M * D_H * 2);
    unsigned char*  h8    = (unsigned char*)alloc((size_t)M * D_H);
    unsigned short* mean2 = (unsigned short*)alloc((size_t)M * D_H * 2);

    // CSR build (no device-scope atomics) + conversions
    const int nx4 = (M * D_IN) / 4;
    const int nw14 = (D_H * D_IN) / 4;
    const int nw24 = (D_H * D_H) / 4;
    const int tot4 = nx4 + 2 * nw14 + 2 * nw24;
    const int convblk = (tot4 + 255) / 256;
    p1_hist_conv_k<<<NBLK + convblk, 256, 0, stream>>>(
        dst, cnt2d, E, NB,
        x, xb8, nx4, W1l, w1lb, W1r, w1rb, nw14, W2l, w2lb, W2r, w2rb, nw24);
    bucket_scan_k<<<NB, NBLK, 0, stream>>>(cnt2d, off2d, tot, NB);
    place_k<<<NBLK, 256, 0, stream>>>(src, dst, cnt2d, off2d, tot, staging, E, NB);
    bucket_sort_k<<<NB, 256, 0, stream>>>(staging, tot, rp, col, M, NB);

    const int nblk = (M + 63) / 64;         // 782 blocks: ~3 blocks/CU
    const int ablk = (M + 3) / 4;

    // layer 1 (gather from fp8 xb8; self path f32 x converted in staging)
    aggregate1_k<<<ablk, 256, 0, stream>>>(xb8, col, rp, mean1, M);
    gemm_mfma_k<D_IN, false, true><<<nblk, 256, 0, stream>>>(
        mean1, w1lb, nullptr, x, w1rb, b1, h1, h8, nullptr, nullptr, nullptr, M);

    // layer 2 + fused head (gather from fp8 h8; self path bf16 h1)
    aggregate2_k<<<ablk, 256, 0, stream>>>(h8, col, rp, mean2, M);
    gemm_mfma_k<D_H, true, false><<<nblk, 256, 0, stream>>>(
        mean2, w2lb, h1, nullptr, w2rb, b2, nullptr, nullptr, hw, hb, out, M);
}